// Round 5
// baseline (93.844 us; speedup 1.0000x reference)
//
#include <hip/hip_runtime.h>

#define M 256
#define N 768
#define K 768

// ws layout (bytes)
#define WS_PARTX 0        // 256 f32 per-block |x| maxes
#define WS_PARTW 1024     // 256 f32 per-block |w| maxes
#define WS_LUT16 4096     // 131072 B: LUT as int16
#define WS_WP    135168   // 589824 B: wP[k4*768 + j] = packed 4 offset-bytes of w[j][4k4..4k4+3]

#define TI 4
#define TJ 192
#define NTH 768

#define SM_LUT 131072
#define SM_XI  (SM_LUT)            // 768 dwords (packed xi, 4 rows per k)
#define SM_RED (SM_LUT + 3072)     // 768*4 int32 partials
#define SM_SC  (SM_RED + 12288)    // 2 floats (sx, sw)
#define SMEM_BYTES (SM_SC + 8)     // 146440

__global__ void absmax_lut_kernel(const float* __restrict__ x,
                                  const float* __restrict__ w,
                                  const int* __restrict__ lut,
                                  unsigned char* __restrict__ wsb) {
    const int tid = threadIdx.x, bid = blockIdx.x;
    // LUT int32 -> int16 (values fit: |prod+noise| <= 16392): 256 entries/block
    if (tid < 128) {
        int e = bid * 128 + tid;
        int2 v = ((const int2*)lut)[e];
        ((unsigned*)(wsb + WS_LUT16))[e] =
            ((unsigned)v.x & 0xFFFFu) | ((unsigned)v.y << 16);
    }
    int gid = bid * 256 + tid;
    const int stride = 256 * 256;
    float mx = 0.f, mw = 0.f;
    const float4* x4 = (const float4*)x;
    const float4* w4 = (const float4*)w;
    for (int i = gid; i < (M * K) / 4; i += stride) {
        float4 v = x4[i];
        mx = fmaxf(mx, fmaxf(fmaxf(fabsf(v.x), fabsf(v.y)),
                             fmaxf(fabsf(v.z), fabsf(v.w))));
    }
    for (int i = gid; i < (N * K) / 4; i += stride) {
        float4 v = w4[i];
        mw = fmaxf(mw, fmaxf(fmaxf(fabsf(v.x), fabsf(v.y)),
                             fmaxf(fabsf(v.z), fabsf(v.w))));
    }
    #pragma unroll
    for (int o = 32; o > 0; o >>= 1) {
        mx = fmaxf(mx, __shfl_down(mx, o, 64));
        mw = fmaxf(mw, __shfl_down(mw, o, 64));
    }
    __shared__ float sred[8];
    if ((tid & 63) == 0) { sred[tid >> 6] = mx; sred[4 + (tid >> 6)] = mw; }
    __syncthreads();
    if (tid == 0) {
        ((float*)(wsb + WS_PARTX))[bid] =
            fmaxf(fmaxf(sred[0], sred[1]), fmaxf(sred[2], sred[3]));
        ((float*)(wsb + WS_PARTW))[bid] =
            fmaxf(fmaxf(sred[4], sred[5]), fmaxf(sred[6], sred[7]));
    }
}

__global__ void wquant_kernel(const float* __restrict__ w,
                              unsigned char* __restrict__ wsb) {
    __shared__ float s_sw;
    const int tid = threadIdx.x;
    const float* partW = (const float*)(wsb + WS_PARTW);
    if (tid < 64) {
        float m = fmaxf(fmaxf(partW[tid], partW[tid + 64]),
                        fmaxf(partW[tid + 128], partW[tid + 192]));
        #pragma unroll
        for (int o = 32; o > 0; o >>= 1) m = fmaxf(m, __shfl_down(m, o, 64));
        if (tid == 0) s_sw = m / 127.f;
    }
    __syncthreads();
    const float sw = s_sw;
    int gid = blockIdx.x * 512 + tid;           // 0..147455, one dword each
    int k4 = gid / 768;
    int j  = gid - k4 * 768;
    float4 v = *(const float4*)(w + j * K + k4 * 4);
    unsigned q0 = (unsigned)((int)fminf(fmaxf(rintf(v.x / sw), -127.f), 127.f) + 128);
    unsigned q1 = (unsigned)((int)fminf(fmaxf(rintf(v.y / sw), -127.f), 127.f) + 128);
    unsigned q2 = (unsigned)((int)fminf(fmaxf(rintf(v.z / sw), -127.f), 127.f) + 128);
    unsigned q3 = (unsigned)((int)fminf(fmaxf(rintf(v.w / sw), -127.f), 127.f) + 128);
    ((unsigned*)(wsb + WS_WP))[gid] = q0 | (q1 << 8) | (q2 << 16) | (q3 << 24);
}

__global__ void __launch_bounds__(NTH, 1)
lutmm_kernel(const float* __restrict__ x,
             const float* __restrict__ bias,
             const unsigned char* __restrict__ wsb,
             float* __restrict__ out) {
    extern __shared__ char smem[];
    short*    lutS = (short*)smem;
    unsigned* xiS  = (unsigned*)(smem + SM_XI);
    int*      red  = (int*)(smem + SM_RED);
    float*    scS  = (float*)(smem + SM_SC);

    const int tid  = threadIdx.x;
    const int row0 = blockIdx.x * TI;
    const int col0 = blockIdx.y * TJ;

    // scales from per-block partials (max is order-independent -> bit-exact)
    if (tid < 64) {
        const float* pX = (const float*)(wsb + WS_PARTX);
        const float* pW = (const float*)(wsb + WS_PARTW);
        float a = fmaxf(fmaxf(pX[tid], pX[tid + 64]), fmaxf(pX[tid + 128], pX[tid + 192]));
        float b = fmaxf(fmaxf(pW[tid], pW[tid + 64]), fmaxf(pW[tid + 128], pW[tid + 192]));
        #pragma unroll
        for (int o = 32; o > 0; o >>= 1) {
            a = fmaxf(a, __shfl_down(a, o, 64));
            b = fmaxf(b, __shfl_down(b, o, 64));
        }
        if (tid == 0) { scS[0] = a / 127.f; scS[1] = b / 127.f; }
    }
    // copy pre-converted int16 LUT: 8192 uint4
    {
        const uint4* g = (const uint4*)(wsb + WS_LUT16);
        uint4* d = (uint4*)lutS;
        #pragma unroll
        for (int it = 0; it < 11; ++it) {
            int i = tid + it * NTH;
            if (i < 8192) d[i] = g[i];
        }
    }
    __syncthreads();
    const float sx = scS[0], sw = scS[1];

    // quantize this block's 4 x-rows, pack 4 rows per k into one dword
    {
        unsigned pk = 0;
        #pragma unroll
        for (int r = 0; r < 4; ++r) {
            float q = rintf(x[(row0 + r) * K + tid] / sx);
            q = fminf(fmaxf(q, -127.f), 127.f);
            pk |= ((unsigned)((int)q + 128)) << (r * 8);
        }
        xiS[tid] = pk;
    }
    __syncthreads();

    const int kp = tid / 192;        // wave-uniform (192 = 3 waves)
    const int j  = tid - kp * 192;
    const int cw = col0 + j;
    const int c0 = kp * 48;
    const unsigned* wP = (const unsigned*)(wsb + WS_WP);
    const uint4* xiS4 = (const uint4*)xiS;

    // 16 independent accumulators (all indices compile-time -> registers)
    int acc[4][4];
    #pragma unroll
    for (int r = 0; r < 4; ++r)
        #pragma unroll
        for (int u = 0; u < 4; ++u) acc[r][u] = 0;

    #pragma unroll 2
    for (int c = 0; c < 48; ++c) {
        unsigned wv = wP[(c0 + c) * 768 + cw];   // coalesced dword (4 k-bytes)
        uint4    xv = xiS4[c0 + c];              // wave-uniform broadcast b128
        #pragma unroll
        for (int u = 0; u < 4; ++u) {
            const short* lp = lutS + ((wv >> (u * 8)) & 255u);  // base + wb
            unsigned xd = (&xv.x)[u];
            acc[0][u] += lp[((xd      ) & 255u) << 8];
            acc[1][u] += lp[((xd >>  8) & 255u) << 8];
            acc[2][u] += lp[((xd >> 16) & 255u) << 8];
            acc[3][u] += lp[((xd >> 24)       ) << 8];
        }
    }

    #pragma unroll
    for (int r = 0; r < 4; ++r) {
        red[tid * 4 + r] = acc[r][0] + acc[r][1] + acc[r][2] + acc[r][3];
    }
    __syncthreads();
    // thread (kp, j) emits output row (row0+kp), col cw
    int s = red[(0 * 192 + j) * 4 + kp] + red[(1 * 192 + j) * 4 + kp]
          + red[(2 * 192 + j) * 4 + kp] + red[(3 * 192 + j) * 4 + kp];
    out[(row0 + kp) * N + cw] = (float)s * (sx * sw) + bias[cw];
}

extern "C" void kernel_launch(void* const* d_in, const int* in_sizes, int n_in,
                              void* d_out, int out_size, void* d_ws, size_t ws_size,
                              hipStream_t stream) {
    const float* x    = (const float*)d_in[0];
    const float* w    = (const float*)d_in[1];
    const float* bias = (const float*)d_in[2];
    const int*   lut  = (const int*)d_in[3];
    float* out = (float*)d_out;
    unsigned char* wsb = (unsigned char*)d_ws;

    absmax_lut_kernel<<<256, 256, 0, stream>>>(x, w, lut, wsb);
    wquant_kernel<<<288, 512, 0, stream>>>(w, wsb);
    hipFuncSetAttribute((const void*)lutmm_kernel,
                        hipFuncAttributeMaxDynamicSharedMemorySize, SMEM_BYTES);
    lutmm_kernel<<<dim3(M / TI, N / TJ), NTH, SMEM_BYTES, stream>>>(
        x, bias, wsb, out);
}